// Round 1
// baseline (1023.706 us; speedup 1.0000x reference)
//
#include <hip/hip_runtime.h>

#define N 1024
#define D 2048
#define P 8
#define F 9          // 1 global + 8 partial features per sample
#define BT 64        // GEMM tile (BT x BT)
#define BK 16        // K-chunk
#define MARGIN 0.3f

__device__ __forceinline__ const float* feat_row(const float* __restrict__ g,
                                                 const float* __restrict__ p,
                                                 int i, int f) {
    return (f == 0) ? (g + (size_t)i * D)
                    : (p + ((size_t)i * P + (f - 1)) * D);
}

// inv[i*F+f] = label_scale / (||row|| + 1e-12)
__global__ void norm_kernel(const float* __restrict__ gfeat,
                            const float* __restrict__ pfeat,
                            const float* __restrict__ plab,
                            float* __restrict__ inv) {
    const int r = blockIdx.x;
    const int i = r / F, f = r % F;
    const float* src = feat_row(gfeat, pfeat, i, f);
    const int t = threadIdx.x;
    const float4* s4 = (const float4*)src;   // 512 float4 per row
    float4 a = s4[t];
    float4 b = s4[t + 256];
    float ss = a.x*a.x + a.y*a.y + a.z*a.z + a.w*a.w
             + b.x*b.x + b.y*b.y + b.z*b.z + b.w*b.w;
    __shared__ float red[256];
    red[t] = ss;
    __syncthreads();
    for (int s = 128; s > 0; s >>= 1) {
        if (t < s) red[t] += red[t + s];
        __syncthreads();
    }
    if (t == 0) {
        float ls = (f == 0) ? 1.0f : plab[i * P + (f - 1)];
        inv[r] = ls / (sqrtf(red[0]) + 1e-12f);
    }
}

// dist[i][j] = 0.5 - (v_i . v_j) / (2*(ov_ij+1)); v = label-scaled normalized rows
__global__ void dist_kernel(const float* __restrict__ gfeat,
                            const float* __restrict__ pfeat,
                            const float* __restrict__ plab,
                            const float* __restrict__ inv,
                            float* __restrict__ dist) {
    __shared__ float As[BK][BT];
    __shared__ float Bs[BK][BT];
    __shared__ float aI[BT][P];
    __shared__ float aJ[BT][P];

    const int i0 = blockIdx.y * BT;
    const int j0 = blockIdx.x * BT;
    const int t = threadIdx.x;

    for (int idx = t; idx < BT * P; idx += 256) {
        int r = idx >> 3, c = idx & 7;
        aI[r][c] = plab[(i0 + r) * P + c];
        aJ[r][c] = plab[(j0 + r) * P + c];
    }

    const int lr = t >> 2;   // load row within tile (0..63)
    const int lq = t & 3;    // float4 slot within BK (k = lq*4..lq*4+3)
    const int tx = t & 15;   // micro-tile col group
    const int ty = t >> 4;   // micro-tile row group

    float acc[4][4] = {{0.f}};

    for (int f = 0; f < F; ++f) {
        const float* baseA = feat_row(gfeat, pfeat, i0 + lr, f);
        const float* baseB = feat_row(gfeat, pfeat, j0 + lr, f);
        const float invA = inv[(i0 + lr) * F + f];
        const float invB = inv[(j0 + lr) * F + f];
        for (int k0 = 0; k0 < D; k0 += BK) {
            float4 va = *(const float4*)(baseA + k0 + lq * 4);
            float4 vb = *(const float4*)(baseB + k0 + lq * 4);
            __syncthreads();             // previous iteration's readers done
            As[lq*4+0][lr] = va.x * invA;
            As[lq*4+1][lr] = va.y * invA;
            As[lq*4+2][lr] = va.z * invA;
            As[lq*4+3][lr] = va.w * invA;
            Bs[lq*4+0][lr] = vb.x * invB;
            Bs[lq*4+1][lr] = vb.y * invB;
            Bs[lq*4+2][lr] = vb.z * invB;
            Bs[lq*4+3][lr] = vb.w * invB;
            __syncthreads();
            #pragma unroll
            for (int k = 0; k < BK; ++k) {
                float4 a4 = ((const float4*)As[k])[ty];
                float4 b4 = ((const float4*)Bs[k])[tx];
                float am[4] = {a4.x, a4.y, a4.z, a4.w};
                float bn[4] = {b4.x, b4.y, b4.z, b4.w};
                #pragma unroll
                for (int m = 0; m < 4; ++m)
                    #pragma unroll
                    for (int nn = 0; nn < 4; ++nn)
                        acc[m][nn] += am[m] * bn[nn];
            }
        }
    }

    #pragma unroll
    for (int m = 0; m < 4; ++m) {
        const int ii = ty * 4 + m;
        float res[4];
        #pragma unroll
        for (int nn = 0; nn < 4; ++nn) {
            const int jj = tx * 4 + nn;
            float ov = 0.f;
            #pragma unroll
            for (int c = 0; c < P; ++c) ov += aI[ii][c] * aJ[jj][c];
            res[nn] = 0.5f - acc[m][nn] / (2.0f * (ov + 1.0f));
        }
        float4 o = {res[0], res[1], res[2], res[3]};
        *(float4*)&dist[(size_t)(i0 + ii) * N + (j0 + tx * 4)] = o;
    }
}

// per-row hardest positive/negative + margin loss
__global__ void mine_kernel(const float* __restrict__ dist,
                            const int* __restrict__ glab,
                            float* __restrict__ rowloss) {
    const int i = blockIdx.x;
    const int t = threadIdx.x;
    const int li = glab[i];
    float ap = -1e30f, an = 1e30f;
    for (int j = t; j < N; j += 256) {
        float d = dist[(size_t)i * N + j];
        if (glab[j] == li) ap = fmaxf(ap, d);
        else               an = fminf(an, d);
    }
    __shared__ float smax[256], smin[256];
    smax[t] = ap; smin[t] = an;
    __syncthreads();
    for (int s = 128; s > 0; s >>= 1) {
        if (t < s) {
            smax[t] = fmaxf(smax[t], smax[t + s]);
            smin[t] = fminf(smin[t], smin[t + s]);
        }
        __syncthreads();
    }
    if (t == 0) rowloss[i] = fmaxf(0.f, smax[0] - smin[0] + MARGIN);
}

__global__ void reduce_kernel(const float* __restrict__ rowloss,
                              float* __restrict__ out) {
    const int t = threadIdx.x;
    float s = rowloss[t] + rowloss[t + 256] + rowloss[t + 512] + rowloss[t + 768];
    __shared__ float red[256];
    red[t] = s;
    __syncthreads();
    for (int st = 128; st > 0; st >>= 1) {
        if (t < st) red[t] += red[t + st];
        __syncthreads();
    }
    if (t == 0) out[0] = red[0] * (1.0f / N);
}

extern "C" void kernel_launch(void* const* d_in, const int* in_sizes, int n_in,
                              void* d_out, int out_size, void* d_ws, size_t ws_size,
                              hipStream_t stream) {
    const float* gfeat = (const float*)d_in[0];
    const float* pfeat = (const float*)d_in[1];
    const float* plab  = (const float*)d_in[2];
    const int*   glab  = (const int*)d_in[3];
    float* out = (float*)d_out;

    char* ws = (char*)d_ws;
    float* inv     = (float*)ws;                 // 9216 floats  (36864 B)
    float* rowloss = (float*)(ws + 36864);       // 1024 floats  (4096 B)
    float* dist    = (float*)(ws + 40960);       // 1024*1024 floats (4 MiB)

    norm_kernel<<<N * F, 256, 0, stream>>>(gfeat, pfeat, plab, inv);
    dist_kernel<<<dim3(N / BT, N / BT), 256, 0, stream>>>(gfeat, pfeat, plab, inv, dist);
    mine_kernel<<<N, 256, 0, stream>>>(dist, glab, rowloss);
    reduce_kernel<<<1, 256, 0, stream>>>(rowloss, out);
}

// Round 2
// 171.631 us; speedup vs baseline: 5.9646x; 5.9646x over previous
//
#include <hip/hip_runtime.h>

#define N 1024
#define D 2048
#define P 8
#define F 9
#define KTOT (F * D)          // 18432
#define SPLIT 8
#define KS (KTOT / SPLIT)     // 2304
#define BM 128                // tile M = N = 128
#define BKT 32                // K per step (16x16x32 MFMA)
#define MARGIN 0.3f

typedef float f32x4 __attribute__((ext_vector_type(4)));
typedef short s16x8 __attribute__((ext_vector_type(8)));

#define GLOBAL_AS __attribute__((address_space(1)))
#define LDS_AS __attribute__((address_space(3)))

__device__ __forceinline__ const float* feat_row(const float* __restrict__ g,
                                                 const float* __restrict__ p,
                                                 int i, int f) {
    return (f == 0) ? (g + (size_t)i * D)
                    : (p + ((size_t)i * P + (f - 1)) * D);
}

__device__ __forceinline__ unsigned f2bf(float x) {
    unsigned u = __float_as_uint(x);
    return (u + 0x7fffu + ((u >> 16) & 1u)) >> 16;   // RNE
}

// One block per (i,f) row: compute 1/(||row||+eps) * label, scale, convert to
// bf16, store into V[(i*F+f)*D + k]  (== concat layout V[i][f*D+k]).
__global__ void pack_kernel(const float* __restrict__ gfeat,
                            const float* __restrict__ pfeat,
                            const float* __restrict__ plab,
                            unsigned short* __restrict__ V) {
    const int r = blockIdx.x;
    const int i = r / F, f = r % F;
    const float* src = feat_row(gfeat, pfeat, i, f);
    const int t = threadIdx.x;
    const float4* s4 = (const float4*)src;
    float4 a = s4[2 * t];
    float4 b = s4[2 * t + 1];
    float ss = a.x*a.x + a.y*a.y + a.z*a.z + a.w*a.w
             + b.x*b.x + b.y*b.y + b.z*b.z + b.w*b.w;
    __shared__ float red[256];
    __shared__ float invs;
    red[t] = ss;
    __syncthreads();
    for (int s = 128; s > 0; s >>= 1) {
        if (t < s) red[t] += red[t + s];
        __syncthreads();
    }
    if (t == 0) {
        float ls = (f == 0) ? 1.0f : plab[i * P + (f - 1)];
        invs = ls / (sqrtf(red[0]) + 1e-12f);
    }
    __syncthreads();
    const float inv = invs;
    uint4 o;
    o.x = f2bf(a.x * inv) | (f2bf(a.y * inv) << 16);
    o.y = f2bf(a.z * inv) | (f2bf(a.w * inv) << 16);
    o.z = f2bf(b.x * inv) | (f2bf(b.y * inv) << 16);
    o.w = f2bf(b.z * inv) | (f2bf(b.w * inv) << 16);
    *(uint4*)&V[(size_t)r * D + t * 8] = o;
}

// C = V * V^T, bf16 MFMA, 128x128 tile, split-K. part[bz][i][j] = partial dot.
__global__ __launch_bounds__(256)
void gemm_kernel(const unsigned short* __restrict__ V,
                 float* __restrict__ part) {
    __shared__ short As[BM * BKT];   // 8 KB, row-major [row][k], 64 B rows
    __shared__ short Bs[BM * BKT];   // 8 KB

    const int t = threadIdx.x;
    const int wave = t >> 6, lane = t & 63;
    const int i0 = blockIdx.y * BM;
    const int j0 = blockIdx.x * BM;
    const int kbase = blockIdx.z * KS;

    // staging source: thread t covers tile row t>>2, 16B chunk (t&3)
    const unsigned short* Ap = V + (size_t)(i0 + (t >> 2)) * KTOT + kbase + (t & 3) * 8;
    const unsigned short* Bp = V + (size_t)(j0 + (t >> 2)) * KTOT + kbase + (t & 3) * 8;

    // fragment read bases (LDS, short elems)
    const int kq = lane >> 4;                       // 0..3 -> k = kq*8..kq*8+7
    const short* Abase = As + ((wave & 1) * 64 + (lane & 15)) * BKT + kq * 8;
    const short* Bbase = Bs + ((wave >> 1) * 64 + (lane & 15)) * BKT + kq * 8;

    f32x4 acc[4][4];
    #pragma unroll
    for (int m = 0; m < 4; ++m)
        #pragma unroll
        for (int n = 0; n < 4; ++n)
            acc[m][n] = (f32x4){0.f, 0.f, 0.f, 0.f};

    for (int ks = 0; ks < KS / BKT; ++ks) {
        __syncthreads();   // previous iteration's readers done
        __builtin_amdgcn_global_load_lds((const GLOBAL_AS void*)Ap,
                                         (LDS_AS void*)(As + t * 8), 16, 0, 0);
        __builtin_amdgcn_global_load_lds((const GLOBAL_AS void*)(Ap + (size_t)64 * KTOT),
                                         (LDS_AS void*)(As + 2048 + t * 8), 16, 0, 0);
        __builtin_amdgcn_global_load_lds((const GLOBAL_AS void*)Bp,
                                         (LDS_AS void*)(Bs + t * 8), 16, 0, 0);
        __builtin_amdgcn_global_load_lds((const GLOBAL_AS void*)(Bp + (size_t)64 * KTOT),
                                         (LDS_AS void*)(Bs + 2048 + t * 8), 16, 0, 0);
        Ap += BKT;
        Bp += BKT;
        __syncthreads();   // staging complete (compiler drains vmcnt before barrier)

        s16x8 af[4], bf[4];
        #pragma unroll
        for (int m = 0; m < 4; ++m) af[m] = *(const s16x8*)(Abase + m * 16 * BKT);
        #pragma unroll
        for (int n = 0; n < 4; ++n) bf[n] = *(const s16x8*)(Bbase + n * 16 * BKT);
        #pragma unroll
        for (int m = 0; m < 4; ++m)
            #pragma unroll
            for (int n = 0; n < 4; ++n)
                acc[m][n] = __builtin_amdgcn_mfma_f32_16x16x32_bf16(
                    af[m], bf[n], acc[m][n], 0, 0, 0);
    }

    // C/D layout: col = lane&15, row = (lane>>4)*4 + reg   [m89-verified]
    float* outp = part + (size_t)blockIdx.z * N * N;
    const int rbase = i0 + (wave & 1) * 64 + (lane >> 4) * 4;
    const int cbase = j0 + (wave >> 1) * 64 + (lane & 15);
    #pragma unroll
    for (int m = 0; m < 4; ++m)
        #pragma unroll
        for (int n = 0; n < 4; ++n)
            #pragma unroll
            for (int r = 0; r < 4; ++r)
                outp[(size_t)(rbase + m * 16 + r) * N + cbase + n * 16] = acc[m][n][r];
}

// fused: sum split-K partials -> dist -> hardest pos/neg per row
__global__ void mine_kernel(const float* __restrict__ part,
                            const float* __restrict__ plab,
                            const int* __restrict__ glab,
                            float* __restrict__ rowloss) {
    const int i = blockIdx.x;
    const int t = threadIdx.x;
    const int li = glab[i];
    float lab_i[P];
    #pragma unroll
    for (int c = 0; c < P; ++c) lab_i[c] = plab[i * P + c];

    float ap = -1e30f, an = 1e30f;
    for (int j = t; j < N; j += 256) {
        float dot = 0.f;
        #pragma unroll
        for (int s = 0; s < SPLIT; ++s)
            dot += part[(size_t)s * N * N + (size_t)i * N + j];
        float ov = 0.f;
        #pragma unroll
        for (int c = 0; c < P; ++c) ov += lab_i[c] * plab[j * P + c];
        float d = 0.5f - dot / (2.0f * (ov + 1.0f));
        if (glab[j] == li) ap = fmaxf(ap, d);
        else               an = fminf(an, d);
    }
    __shared__ float smax[256], smin[256];
    smax[t] = ap; smin[t] = an;
    __syncthreads();
    for (int s = 128; s > 0; s >>= 1) {
        if (t < s) {
            smax[t] = fmaxf(smax[t], smax[t + s]);
            smin[t] = fminf(smin[t], smin[t + s]);
        }
        __syncthreads();
    }
    if (t == 0) rowloss[i] = fmaxf(0.f, smax[0] - smin[0] + MARGIN);
}

__global__ void reduce_kernel(const float* __restrict__ rowloss,
                              float* __restrict__ out) {
    const int t = threadIdx.x;
    float s = rowloss[t] + rowloss[t + 256] + rowloss[t + 512] + rowloss[t + 768];
    __shared__ float red[256];
    red[t] = s;
    __syncthreads();
    for (int st = 128; st > 0; st >>= 1) {
        if (t < st) red[t] += red[t + st];
        __syncthreads();
    }
    if (t == 0) out[0] = red[0] * (1.0f / N);
}

extern "C" void kernel_launch(void* const* d_in, const int* in_sizes, int n_in,
                              void* d_out, int out_size, void* d_ws, size_t ws_size,
                              hipStream_t stream) {
    const float* gfeat = (const float*)d_in[0];
    const float* pfeat = (const float*)d_in[1];
    const float* plab  = (const float*)d_in[2];
    const int*   glab  = (const int*)d_in[3];
    float* out = (float*)d_out;

    char* ws = (char*)d_ws;
    unsigned short* V = (unsigned short*)ws;                 // 1024*18432*2 = 37,748,736 B
    float* part    = (float*)(ws + (size_t)37748736);        // 8*1024*1024*4 = 33,554,432 B
    float* rowloss = (float*)(ws + (size_t)37748736 + 33554432);  // 4096 B

    pack_kernel<<<N * F, 256, 0, stream>>>(gfeat, pfeat, plab, V);
    gemm_kernel<<<dim3(N / BM, N / BM, SPLIT), 256, 0, stream>>>(V, part);
    mine_kernel<<<N, 256, 0, stream>>>(part, plab, glab, rowloss);
    reduce_kernel<<<1, 256, 0, stream>>>(rowloss, out);
}